// Round 11
// baseline (242.038 us; speedup 1.0000x reference)
//
#include <hip/hip_runtime.h>
#include <math.h>

#define N_TOTAL 40960
#define M_EV    4096
#define KNN     32
#define FEAT    192   // CIN + 2*PDIM

__device__ __forceinline__ float dot4f(float4 a, float4 b) {
    return fmaf(a.w, b.w, fmaf(a.z, b.z, fmaf(a.y, b.y, a.x * b.x)));
}

// lex-ascending bitonic sort of (d,i) across the 64 lanes of a wave
__device__ __forceinline__ void sort64(float &d, int &i, const int l)
{
#pragma unroll
    for (int k = 2; k <= 64; k <<= 1) {
#pragma unroll
        for (int j = k >> 1; j >= 1; j >>= 1) {
            float pd = __shfl_xor(d, j, 64);
            int   pi = __shfl_xor(i, j, 64);
            bool tmn  = (((l & k) == 0) == ((l & j) == 0));
            bool plt  = (pd < d) || (pd == d && pi < i);
            bool keep = tmn ? plt : !plt;
            d = keep ? pd : d;
            i = keep ? pi : i;
        }
    }
}

// ---------------------------------------------------------------------------
// Kernel 1: space = x@W_space + b_space  [N,4];  prop = x@W_prop + b_prop [N,64]
// ---------------------------------------------------------------------------
__global__ __launch_bounds__(256) void k_linear(
    const float* __restrict__ x,
    const float* __restrict__ Wp, const float* __restrict__ bp,
    const float* __restrict__ Ws, const float* __restrict__ bs,
    float* __restrict__ prop, float* __restrict__ space)
{
    __shared__ float xs[16 * 64];
    const int t = threadIdx.x;
    const int rowbase = blockIdx.x * 16;

    {
        float4 v = *(const float4*)(x + rowbase * 64 + t * 4);
        *(float4*)(xs + t * 4) = v;
    }
    __syncthreads();

    const int j  = t & 63;
    const int rg = t >> 6;
    float a0 = 0.f, a1 = 0.f, a2 = 0.f, a3 = 0.f;
#pragma unroll 8
    for (int c = 0; c < 64; ++c) {
        float w = Wp[c * 64 + j];
        a0 = fmaf(xs[(rg * 4 + 0) * 64 + c], w, a0);
        a1 = fmaf(xs[(rg * 4 + 1) * 64 + c], w, a1);
        a2 = fmaf(xs[(rg * 4 + 2) * 64 + c], w, a2);
        a3 = fmaf(xs[(rg * 4 + 3) * 64 + c], w, a3);
    }
    const float bj = bp[j];
    prop[(rowbase + rg * 4 + 0) * 64 + j] = a0 + bj;
    prop[(rowbase + rg * 4 + 1) * 64 + j] = a1 + bj;
    prop[(rowbase + rg * 4 + 2) * 64 + j] = a2 + bj;
    prop[(rowbase + rg * 4 + 3) * 64 + j] = a3 + bj;

    if (t < 64) {
        const int r = t >> 2, s = t & 3;
        float a = 0.f;
#pragma unroll 8
        for (int c = 0; c < 64; ++c)
            a = fmaf(xs[r * 64 + c], Ws[c * 4 + s], a);
        space[(rowbase + r) * 4 + s] = a + bs[s];
    }
}

// ---------------------------------------------------------------------------
// Kernel 2: exact kNN, threshold-compact-sort (UNCHANGED from round 10 — the
// control for this round). 512 thr, 4 q/wave, dh key, index-only compaction.
// ---------------------------------------------------------------------------
#define QPW   4
#define QPB   32
#define TILEC 1024
#define CCAP  128

__global__ __launch_bounds__(512, 1) void k_knn(
    const float4* __restrict__ space4,
    int* __restrict__ knn_idx, float* __restrict__ knn_w,
    int* __restrict__ bad)
{
    __shared__ float4 s_c[TILEC];         // 16384 B
    __shared__ float  s_h[TILEC];         //  4096 B  (0.5*|c|^2)
    __shared__ ushort s_ci[QPB * CCAP];   //  8192 B
    __shared__ int    s_cnt[QPB];         //   128 B  => 28800 B

    const int t = threadIdx.x;
    const int w = t >> 6;
    const int l = t & 63;
    const int qb = blockIdx.x * QPB;
    const int ebase = (qb / M_EV) * M_EV;

    if (t < QPB) s_cnt[t] = 0;           // covered by first tile barrier

    float4 qcs[QPW]; float sqq[QPW];
#pragma unroll
    for (int s = 0; s < QPW; ++s) {
        qcs[s] = space4[qb + w * QPW + s];
        sqq[s] = dot4f(qcs[s], qcs[s]);
    }

    float mn[QPW];
#pragma unroll
    for (int s = 0; s < QPW; ++s) mn[s] = INFINITY;

    // ---- pass 1: per-lane slice minima of dh ----
#pragma unroll 1
    for (int tile = 0; tile < M_EV / TILEC; ++tile) {
        __syncthreads();
#pragma unroll
        for (int u = 0; u < TILEC / 512; ++u) {
            int ci = u * 512 + t;
            float4 c = space4[ebase + tile * TILEC + ci];
            s_c[ci] = c;
            s_h[ci] = 0.5f * dot4f(c, c);
        }
        __syncthreads();
#pragma unroll 4
        for (int j = 0; j < TILEC / 64; ++j) {
            int ci = j * 64 + l;
            float4 c = s_c[ci]; float hc = s_h[ci];
#pragma unroll
            for (int s = 0; s < QPW; ++s) {
                float dh = fmaf(-qcs[s].x, c.x, hc);
                dh = fmaf(-qcs[s].y, c.y, dh);
                dh = fmaf(-qcs[s].z, c.z, dh);
                dh = fmaf(-qcs[s].w, c.w, dh);
                mn[s] = fminf(mn[s], dh);
            }
        }
    }

    // ---- T[s] = 32nd smallest of the 64 lane minima ----
    float v[QPW];
#pragma unroll
    for (int s = 0; s < QPW; ++s) v[s] = mn[s];
#pragma unroll
    for (int k = 2; k <= 64; k <<= 1) {
#pragma unroll
        for (int j = k >> 1; j >= 1; j >>= 1) {
            bool tmn = (((l & k) == 0) == ((l & j) == 0));
#pragma unroll
            for (int s = 0; s < QPW; ++s) {
                float p = __shfl_xor(v[s], j, 64);
                v[s] = tmn ? fminf(v[s], p) : fmaxf(v[s], p);
            }
        }
    }
    float T[QPW];
#pragma unroll
    for (int s = 0; s < QPW; ++s) T[s] = __shfl(v[s], 31, 64);

    // ---- pass 2: compact indices with dh<=T (identical fma chain) ----
#pragma unroll 1
    for (int tile = 0; tile < M_EV / TILEC; ++tile) {
        __syncthreads();
#pragma unroll
        for (int u = 0; u < TILEC / 512; ++u) {
            int ci = u * 512 + t;
            float4 c = space4[ebase + tile * TILEC + ci];
            s_c[ci] = c;
            s_h[ci] = 0.5f * dot4f(c, c);
        }
        __syncthreads();
#pragma unroll 2
        for (int j = 0; j < TILEC / 64; ++j) {
            int ci = j * 64 + l;
            float4 c = s_c[ci]; float hc = s_h[ci];
#pragma unroll
            for (int s = 0; s < QPW; ++s) {
                float dh = fmaf(-qcs[s].x, c.x, hc);
                dh = fmaf(-qcs[s].y, c.y, dh);
                dh = fmaf(-qcs[s].z, c.z, dh);
                dh = fmaf(-qcs[s].w, c.w, dh);
                if (dh <= T[s]) {
                    int p = atomicAdd(&s_cnt[w * QPW + s], 1);
                    if (p < CCAP)
                        s_ci[(w * QPW + s) * CCAP + p] = (ushort)(tile * TILEC + ci);
                }
            }
        }
    }
    // own wave wrote its own compact region; DS ops in-order per wave.

    // ---- exact select per query (fully unrolled: constant s everywhere) ----
#pragma unroll
    for (int s = 0; s < QPW; ++s) {
        const int qi = w * QPW + s;
        const int q  = qb + qi;
        const int cnt = s_cnt[qi];                 // wave-uniform
        if (l == 0) bad[q] = (cnt > CCAP) ? 1 : 0;
        if (cnt <= CCAP) {
            const float4 qc = qcs[s];

            int   iA = (l < cnt) ? (int)s_ci[qi * CCAP + l] : 65535;
            float dA;
            {
                float4 c = space4[ebase + ((l < cnt) ? iA : 0)];
                float hc = 0.5f * dot4f(c, c);
                float dh = fmaf(-qc.x, c.x, hc);
                dh = fmaf(-qc.y, c.y, dh);
                dh = fmaf(-qc.z, c.z, dh);
                dh = fmaf(-qc.w, c.w, dh);
                dA = (l < cnt) ? dh : INFINITY;
            }

            float d; int i;
            if (cnt <= 64) {
                d = dA; i = iA;
                sort64(d, i, l);
            } else {
                int   iB = (64 + l < cnt) ? (int)s_ci[qi * CCAP + 64 + l] : 65535;
                float dB;
                {
                    float4 c = space4[ebase + ((64 + l < cnt) ? iB : 0)];
                    float hc = 0.5f * dot4f(c, c);
                    float dh = fmaf(-qc.x, c.x, hc);
                    dh = fmaf(-qc.y, c.y, dh);
                    dh = fmaf(-qc.z, c.z, dh);
                    dh = fmaf(-qc.w, c.w, dh);
                    dB = (64 + l < cnt) ? dh : INFINITY;
                }
                sort64(dA, iA, l);
                sort64(dB, iB, l);
                float dBr = __shfl(dB, 63 - l, 64);
                int   iBr = __shfl(iB, 63 - l, 64);
                bool bl = (dBr < dA) || (dBr == dA && iBr < iA);
                d = bl ? dBr : dA;
                i = bl ? iBr : iA;
#pragma unroll
                for (int j = 32; j >= 1; j >>= 1) {
                    float pd = __shfl_xor(d, j, 64);
                    int   pi = __shfl_xor(i, j, 64);
                    bool plt  = (pd < d) || (pd == d && pi < i);
                    bool keep = ((l & j) == 0) ? plt : !plt;
                    d = keep ? pd : d;
                    i = keep ? pi : i;
                }
            }

            if (l < KNN) {
                float dt = fmaxf(fmaf(2.0f, d, sqq[s]), 0.0f);
                knn_idx[q * KNN + l] = ebase + i;
                knn_w[q * KNN + l]   = __expf(-10.0f * dt);
            }
        }
    }
}

// ---------------------------------------------------------------------------
// Kernel 2b: exact fallback for flagged queries (expected never to fire).
// ---------------------------------------------------------------------------
__global__ __launch_bounds__(256) void k_fix(
    const float4* __restrict__ space4, const int* __restrict__ bad,
    int* __restrict__ knn_idx, float* __restrict__ knn_w)
{
    const int q = blockIdx.x * 256 + threadIdx.x;
    if (!bad[q]) return;
    const int eb = (q / M_EV) * M_EV;
    float4 qc = space4[q];
    float sqq = dot4f(qc, qc);
    float ld[KNN]; int li[KNN];
    for (int e = 0; e < KNN; ++e) { ld[e] = INFINITY; li[e] = 0; }
    float cm = INFINITY; int mp = 0;
    for (int c = 0; c < M_EV; ++c) {
        float4 cc = space4[eb + c];
        float d = fmaf(-2.0f, dot4f(qc, cc), sqq + dot4f(cc, cc));
        if (d < cm) {
            ld[mp] = d; li[mp] = c;
            cm = ld[0]; mp = 0;
            for (int e = 1; e < KNN; ++e) if (ld[e] > cm) { cm = ld[e]; mp = e; }
        }
    }
    for (int e = 0; e < KNN; ++e) {
        knn_idx[q * KNN + e] = eb + li[e];
        knn_w[q * KNN + e]   = __expf(-10.0f * fmaxf(ld[e], 0.0f));
    }
}

// ---------------------------------------------------------------------------
// Kernel 3 (fused agg+out), v2: 32 queries/block, 4x4 outputs/thread.
//   feat tile transposed, FSTR=36 (mult of 4) -> 4 consecutive rows read as
//   one ds_read_b128 (half-wave broadcast). Inner iter: 1xb128(feat) +
//   1xb128(W) = 32 B per 16 fma = 2 B/fma (was 3). GEMM LDS traffic 3->2 GB.
//   Accumulators are explicit float4s (never an indexable array -- spill rule).
// ---------------------------------------------------------------------------
#define QROWS 32
#define FSTR  36

__global__ __launch_bounds__(256) void k_tail(
    const float* __restrict__ x, const float* __restrict__ prop,
    const int* __restrict__ knn_idx, const float* __restrict__ knn_w,
    const float* __restrict__ Wo, const float* __restrict__ bo,
    float* __restrict__ out)
{
    __shared__ float fs2[FEAT * FSTR];   // 27648 B
    __shared__ float s_w[48 * 128];      // 24576 B  => 52224 B, 3 blocks/CU

    const int t = threadIdx.x;
    const int qb = blockIdx.x * QROWS;

    // A1: x transpose: fs2[i*36 + r] = x[(qb+r)*64 + i]; 512 float4s, 2/thread
#pragma unroll
    for (int u = 0; u < 2; ++u) {
        int f = u * 256 + t;
        int r  = f >> 4;               // 0..31
        int c4 = (f & 15) * 4;
        float4 v = *(const float4*)(x + (size_t)(qb + r) * 64 + c4);
        fs2[(c4 + 0) * FSTR + r] = v.x;
        fs2[(c4 + 1) * FSTR + r] = v.y;
        fs2[(c4 + 2) * FSTR + r] = v.z;
        fs2[(c4 + 3) * FSTR + r] = v.w;
    }

    // A2: aggregation (8 rounds of 4 queries; lane p = prop channel)
    {
        const int p = t & 63;
#pragma unroll 1
        for (int s = 0; s < 8; ++s) {
            const int r = s * 4 + (t >> 6);
            const int q = qb + r;
            float acc = 0.f, mx = -INFINITY;
#pragma unroll 8
            for (int e = 0; e < KNN; ++e) {
                int   ix = knn_idx[q * KNN + e];     // wave-uniform
                float wv = knn_w[q * KNN + e];
                float g  = wv * prop[(size_t)ix * 64 + p];
                acc += g;
                mx = fmaxf(mx, g);
            }
            fs2[(64 + p) * FSTR + r]  = acc * (1.0f / 32.0f);
            fs2[(128 + p) * FSTR + r] = mx;
        }
    }

    // B: GEMM. thread = (4 rows: rq=t>>5 in 0..7) x (4 cols: c4=(t&31)*4)
    const int rq = t >> 5;
    const int c4 = (t & 31) * 4;
    float4 a0 = {0.f, 0.f, 0.f, 0.f};
    float4 a1 = {0.f, 0.f, 0.f, 0.f};
    float4 a2 = {0.f, 0.f, 0.f, 0.f};
    float4 a3 = {0.f, 0.f, 0.f, 0.f};

#pragma unroll 1
    for (int cc = 0; cc < 4; ++cc) {
        __syncthreads();                  // fs2 ready (cc=0) / prev chunk done
#pragma unroll
        for (int u = 0; u < 6; ++u) {     // stage 48x128 W chunk
            int fi = u * 1024 + t * 4;
            *(float4*)(s_w + fi) = *(const float4*)(Wo + (size_t)cc * 48 * 128 + fi);
        }
        __syncthreads();
#pragma unroll 4
        for (int ii = 0; ii < 48; ++ii) {
            int i = cc * 48 + ii;
            float4 f  = *(const float4*)(fs2 + i * FSTR + rq * 4);
            float4 wv = *(const float4*)(s_w + ii * 128 + c4);
            a0.x = fmaf(f.x, wv.x, a0.x); a0.y = fmaf(f.x, wv.y, a0.y);
            a0.z = fmaf(f.x, wv.z, a0.z); a0.w = fmaf(f.x, wv.w, a0.w);
            a1.x = fmaf(f.y, wv.x, a1.x); a1.y = fmaf(f.y, wv.y, a1.y);
            a1.z = fmaf(f.y, wv.z, a1.z); a1.w = fmaf(f.y, wv.w, a1.w);
            a2.x = fmaf(f.z, wv.x, a2.x); a2.y = fmaf(f.z, wv.y, a2.y);
            a2.z = fmaf(f.z, wv.z, a2.z); a2.w = fmaf(f.z, wv.w, a2.w);
            a3.x = fmaf(f.w, wv.x, a3.x); a3.y = fmaf(f.w, wv.y, a3.y);
            a3.z = fmaf(f.w, wv.z, a3.z); a3.w = fmaf(f.w, wv.w, a3.w);
        }
    }

    const float4 bc = *(const float4*)(bo + c4);
    float4 o;
    o.x = fmaxf(a0.x + bc.x, 0.f); o.y = fmaxf(a0.y + bc.y, 0.f);
    o.z = fmaxf(a0.z + bc.z, 0.f); o.w = fmaxf(a0.w + bc.w, 0.f);
    *(float4*)(out + (size_t)(qb + rq * 4 + 0) * 128 + c4) = o;
    o.x = fmaxf(a1.x + bc.x, 0.f); o.y = fmaxf(a1.y + bc.y, 0.f);
    o.z = fmaxf(a1.z + bc.z, 0.f); o.w = fmaxf(a1.w + bc.w, 0.f);
    *(float4*)(out + (size_t)(qb + rq * 4 + 1) * 128 + c4) = o;
    o.x = fmaxf(a2.x + bc.x, 0.f); o.y = fmaxf(a2.y + bc.y, 0.f);
    o.z = fmaxf(a2.z + bc.z, 0.f); o.w = fmaxf(a2.w + bc.w, 0.f);
    *(float4*)(out + (size_t)(qb + rq * 4 + 2) * 128 + c4) = o;
    o.x = fmaxf(a3.x + bc.x, 0.f); o.y = fmaxf(a3.y + bc.y, 0.f);
    o.z = fmaxf(a3.z + bc.z, 0.f); o.w = fmaxf(a3.w + bc.w, 0.f);
    *(float4*)(out + (size_t)(qb + rq * 4 + 3) * 128 + c4) = o;
}

// ---------------------------------------------------------------------------
extern "C" void kernel_launch(void* const* d_in, const int* in_sizes, int n_in,
                              void* d_out, int out_size, void* d_ws, size_t ws_size,
                              hipStream_t stream) {
    const float* x  = (const float*)d_in[0];
    const float* Ws = (const float*)d_in[2];
    const float* bs = (const float*)d_in[3];
    const float* Wp = (const float*)d_in[4];
    const float* bp = (const float*)d_in[5];
    const float* Wo = (const float*)d_in[6];
    const float* bo = (const float*)d_in[7];
    float* out = (float*)d_out;

    float* space = (float*)d_ws;                          // N*4
    float* prop  = space + (size_t)N_TOTAL * 4;           // N*64
    int*   kidx  = (int*)(prop + (size_t)N_TOTAL * 64);   // N*32
    float* kw    = (float*)(kidx + (size_t)N_TOTAL * KNN);// N*32
    int*   bad   = (int*)(kw + (size_t)N_TOTAL * KNN);    // N

    k_linear<<<N_TOTAL / 16, 256, 0, stream>>>(x, Wp, bp, Ws, bs, prop, space);
    k_knn   <<<N_TOTAL / QPB, 512, 0, stream>>>((const float4*)space, kidx, kw, bad);
    k_fix   <<<N_TOTAL / 256, 256, 0, stream>>>((const float4*)space, bad, kidx, kw);
    k_tail  <<<N_TOTAL / QROWS, 256, 0, stream>>>(x, prop, kidx, kw, Wo, bo, out);
}